// Round 4
// baseline (408.805 us; speedup 1.0000x reference)
//
#include <hip/hip_runtime.h>
#include <math.h>

#define H_IMG 2160
#define W_IMG 3840
#define SPAN 252          // output cols per strip (x0+1 .. x0+252; strip 0 also owns col 0)
#define NSX 16            // 16 * 252 = 4032 >= 3840
#define HS 16             // output rows per wave; 2160/16 = 135
#define NSY 135
#define NBLOCKS (NSX * NSY)   // 2160 single-wave blocks
#define NBINS 2048

// Rolling-register fused kernel, one wave per block, no barrier, no LDS tile.
// ALL rolling state is in constant-indexed named arrays rotated by direct
// assignment -> SROA promotes to registers even if the row loop is not
// unrolled (R3's j%3 indexing defeated SROA and spilled to scratch).
__global__ __launch_bounds__(64, 3) void shading_main(
    const float* __restrict__ depth,
    const float* __restrict__ rgb,
    const int*   __restrict__ mask,
    const float* __restrict__ lmat,   // [9][3]
    const float* __restrict__ K,      // [3][3]
    float* __restrict__ accum,        // partial {S,C} pairs
    int direct)
{
    const int lane = threadIdx.x;                  // 0..63
    const int sx   = blockIdx.x;
    const int x0   = sx * SPAN;                    // multiple of 4
    const int y0   = blockIdx.y * HS;
    const int colBase = x0 + 4 * lane;             // 16B-aligned
    const bool fullIn = (colBase + 3) < W_IMG;     // 4-col groups: fully in or fully out

    // ---- Kinv (adjugate/det; uniform -> SGPRs) ----
    const float m00 = K[0], m01 = K[1], m02 = K[2];
    const float m10 = K[3], m11 = K[4], m12 = K[5];
    const float m20 = K[6], m21 = K[7], m22 = K[8];
    const float det = m00*(m11*m22 - m12*m21)
                    - m01*(m10*m22 - m12*m20)
                    + m02*(m10*m21 - m11*m20);
    const float id  = 1.0f / det;
    const float i00 = (m11*m22 - m12*m21) * id;
    const float i01 = (m02*m21 - m01*m22) * id;
    const float i02 = (m01*m12 - m02*m11) * id;
    const float i10 = (m12*m20 - m10*m22) * id;
    const float i11 = (m00*m22 - m02*m20) * id;
    const float i12 = (m02*m10 - m00*m12) * id;
    const float i20 = (m10*m21 - m11*m20) * id;
    const float i21 = (m01*m20 - m00*m21) * id;
    const float i22 = (m00*m11 - m01*m10) * id;

    float L[27];
    #pragma unroll
    for (int i = 0; i < 27; ++i) L[i] = lmat[i];   // uniform -> s_load

    // ---- output ownership: strip owns lc in [1,252] (strip 0 also lc=0) ----
    float wout[4];
    #pragma unroll
    for (int k = 0; k < 4; ++k) {
        const int c  = colBase + k;
        const int lc = 4 * lane + k;
        const bool v = (c < W_IMG) && (lc <= SPAN) && (lc >= 1 || sx == 0);
        wout[k] = v ? 1.0f : 0.0f;
    }
    const float qm1s = (lane == 0) ? 0.0f : 1.0f;  // zero-pad left edge of strip 0

    // ---- ray at (colBase, y0-1); +Kinv col1 per row ----
    float rx = fmaf(i00, (float)colBase, fmaf(i01, (float)(y0 - 1), i02));
    float ry = fmaf(i10, (float)colBase, fmaf(i11, (float)(y0 - 1), i12));
    float rz = fmaf(i20, (float)colBase, fmaf(i21, (float)(y0 - 1), i22));

    // ---- preload depth row y0-1 (value irrelevant if y0==0: q row -1 is 0 via mf/rgb) ----
    float dc[4] = {0.f, 0.f, 0.f, 0.f};
    if (fullIn && y0 > 0) {
        const float4 t = *(const float4*)(depth + (long)(y0 - 1) * W_IMG + colBase);
        dc[0] = t.x; dc[1] = t.y; dc[2] = t.z; dc[3] = t.w;
    }

    // rolling state (explicit slots, constant indices only)
    float sA0[4] = {0,0,0,0}, sA1[4] = {0,0,0,0}, sA2[4] = {0,0,0,0};  // sums row h-2
    float sB0[4] = {0,0,0,0}, sB1[4] = {0,0,0,0}, sB2[4] = {0,0,0,0};  // sums row h-1
    float qB0[4] = {0,0,0,0}, qB1[4] = {0,0,0,0}, qB2[4] = {0,0,0,0};  // centers row h-1
    float wB[4]  = {0,0,0,0};
    float accS = 0.f, accC = 0.f;

    #pragma unroll
    for (int j = 0; j < HS + 2; ++j) {
        const int h  = y0 - 1 + j;      // row shaded this step
        const int hn = h + 1;

        // ---- loads (zero outside image; then q = mf*B - rgb = 0 there) ----
        float dn[4] = {0.f, 0.f, 0.f, 0.f};
        float rr[12] = {0,0,0,0,0,0,0,0,0,0,0,0};
        float mf[4] = {0.f, 0.f, 0.f, 0.f};
        if (fullIn) {
            if (hn < H_IMG) {           // hn >= 0 always
                const float4 t = *(const float4*)(depth + (long)hn * W_IMG + colBase);
                dn[0] = t.x; dn[1] = t.y; dn[2] = t.z; dn[3] = t.w;
            }
            if ((unsigned)h < (unsigned)H_IMG) {
                const long pix = (long)h * W_IMG + colBase;
                const float4 a  = *(const float4*)(rgb + pix * 3);
                const float4 b  = *(const float4*)(rgb + pix * 3 + 4);
                const float4 cc = *(const float4*)(rgb + pix * 3 + 8);
                const int4   mm = *(const int4*)(mask + pix);
                rr[0] = a.x;  rr[1] = a.y;  rr[2]  = a.z;
                rr[3] = a.w;  rr[4] = b.x;  rr[5]  = b.y;
                rr[6] = b.z;  rr[7] = b.w;  rr[8]  = cc.x;
                rr[9] = cc.y; rr[10] = cc.z; rr[11] = cc.w;
                mf[0] = mm.x > 0 ? 1.f : 0.f;
                mf[1] = mm.y > 0 ? 1.f : 0.f;
                mf[2] = mm.z > 0 ? 1.f : 0.f;
                mf[3] = mm.w > 0 ? 1.f : 0.f;
            }
        }
        const float dcR = __shfl_down(dc[0], 1, 64);   // depth(h, colBase+4)

        // ---- shade 4 cols -> qC (current row) ----
        float qC0[4], qC1[4], qC2[4], wC[4];
        float rxk = rx, ryk = ry, rzk = rz;
        #pragma unroll
        for (int k = 0; k < 4; ++k) {
            const float d0 = dc[k];
            const float dR = (k < 3) ? dc[k + 1] : dcR;
            const float dD = dn[k];
            const float px = rxk * d0, py = ryk * d0, pz = rzk * d0;
            const float ax = (rxk + i00) * dR - px;    // pl - p
            const float ay = (ryk + i10) * dR - py;
            const float az = (rzk + i20) * dR - pz;
            const float bx = (rxk + i01) * dD - px;    // pu - p
            const float by = (ryk + i11) * dD - py;
            const float bz = (rzk + i21) * dD - pz;
            float nx = ay*bz - az*by;
            float ny = az*bx - ax*bz;
            float nz = ax*by - ay*bx;
            const float nn  = nx*nx + ny*ny + nz*nz;
            const float inr = __builtin_amdgcn_rsqf(fmaxf(nn, 1e-24f)); // ==1/max(sqrt,1e-12)
            nx *= inr; ny *= inr; nz *= inr;
            const float h4 = nx*ny, h5 = ny*nz, h7 = nz*nx;
            const float nx2 = nx*nx, ny2 = ny*ny, nz2 = nz*nz;
            const float h6 = 2.f*nz2 - nx2 - ny2;
            const float h8 = nx2 - ny2;
            const float B0 = L[0] + ny*L[3] + nz*L[6] + nx*L[9]  + h4*L[12] + h5*L[15] + h6*L[18] + h7*L[21] + h8*L[24];
            const float B1 = L[1] + ny*L[4] + nz*L[7] + nx*L[10] + h4*L[13] + h5*L[16] + h6*L[19] + h7*L[22] + h8*L[25];
            const float B2 = L[2] + ny*L[5] + nz*L[8] + nx*L[11] + h4*L[14] + h5*L[17] + h6*L[20] + h7*L[23] + h8*L[26];
            const float m  = mf[k];
            qC0[k] = fmaf(m, B0, -rr[3*k + 0]);        // q = mask*B - rgb
            qC1[k] = fmaf(m, B1, -rr[3*k + 1]);
            qC2[k] = fmaf(m, B2, -rr[3*k + 2]);
            wC[k]  = m * wout[k];
            rxk += i00; ryk += i10; rzk += i20;        // +Kinv col0 per col
        }

        // ---- horizontal 3-tap sums via shuffles -> sC ----
        float sC0[4], sC1[4], sC2[4];
        {
            const float a0 = __shfl_up(qC0[3], 1, 64) * qm1s;
            const float a1 = __shfl_up(qC1[3], 1, 64) * qm1s;
            const float a2 = __shfl_up(qC2[3], 1, 64) * qm1s;
            const float p0 = __shfl_down(qC0[0], 1, 64);
            const float p1 = __shfl_down(qC1[0], 1, 64);
            const float p2 = __shfl_down(qC2[0], 1, 64);

            const float t01_0 = qC0[0] + qC0[1];
            const float t12_0 = qC0[1] + qC0[2];
            const float t23_0 = qC0[2] + qC0[3];
            sC0[0] = a0 + t01_0;
            sC0[1] = t01_0 + qC0[2];
            sC0[2] = t12_0 + qC0[3];
            sC0[3] = t23_0 + p0;

            const float t01_1 = qC1[0] + qC1[1];
            const float t12_1 = qC1[1] + qC1[2];
            const float t23_1 = qC1[2] + qC1[3];
            sC1[0] = a1 + t01_1;
            sC1[1] = t01_1 + qC1[2];
            sC1[2] = t12_1 + qC1[3];
            sC1[3] = t23_1 + p1;

            const float t01_2 = qC2[0] + qC2[1];
            const float t12_2 = qC2[1] + qC2[2];
            const float t23_2 = qC2[2] + qC2[3];
            sC2[0] = a2 + t01_2;
            sC2[1] = t01_2 + qC2[2];
            sC2[2] = t12_2 + qC2[3];
            sC2[3] = t23_2 + p2;
        }

        // ---- emit row h-1: diff = q - sum3x3/9 ----
        if (j >= 2) {
            #pragma unroll
            for (int k = 0; k < 4; ++k) {
                const float v0 = sA0[k] + sB0[k] + sC0[k];
                const float v1 = sA1[k] + sB1[k] + sC1[k];
                const float v2 = sA2[k] + sB2[k] + sC2[k];
                const float d0 = fmaf(v0, -(1.f/9.f), qB0[k]);
                const float d1 = fmaf(v1, -(1.f/9.f), qB1[k]);
                const float d2 = fmaf(v2, -(1.f/9.f), qB2[k]);
                const float w  = wB[k];
                accS = fmaf(w, d0*d0 + d1*d1 + d2*d2, accS);
                accC += w;
            }
        }

        // ---- rotate (direct assignments: SROA-safe) ----
        #pragma unroll
        for (int k = 0; k < 4; ++k) {
            sA0[k] = sB0[k]; sA1[k] = sB1[k]; sA2[k] = sB2[k];
            sB0[k] = sC0[k]; sB1[k] = sC1[k]; sB2[k] = sC2[k];
            qB0[k] = qC0[k]; qB1[k] = qC1[k]; qB2[k] = qC2[k];
            wB[k]  = wC[k];
            dc[k]  = dn[k];
        }
        rx += i01; ry += i11; rz += i21;               // +Kinv col1 per row
    }

    // ---- single-wave reduction -> store/atomic (no LDS, no barrier) ----
    #pragma unroll
    for (int off = 32; off > 0; off >>= 1) {
        accS += __shfl_down(accS, off, 64);
        accC += __shfl_down(accC, off, 64);
    }
    if (lane == 0) {
        const int bid = blockIdx.y * gridDim.x + blockIdx.x;
        if (direct) {
            accum[2*bid + 0] = accS;
            accum[2*bid + 1] = accC;
        } else {
            const int bin = bid & (NBINS - 1);
            atomicAdd(&accum[2*bin + 0], accS);
            atomicAdd(&accum[2*bin + 1], accC);
        }
    }
}

__global__ __launch_bounds__(256) void finalize_kernel(
    const float* __restrict__ part, int n, float* __restrict__ out)
{
    const int tid = threadIdx.x;
    float s = 0.f, c = 0.f;
    for (int i = tid; i < n; i += 256) {
        s += part[2*i + 0];
        c += part[2*i + 1];
    }
    #pragma unroll
    for (int off = 32; off > 0; off >>= 1) {
        s += __shfl_down(s, off, 64);
        c += __shfl_down(c, off, 64);
    }
    __shared__ float sS[4], sC[4];
    const int wid = tid >> 6, lane = tid & 63;
    if (lane == 0) { sS[wid] = s; sC[wid] = c; }
    __syncthreads();
    if (tid == 0) {
        const float ts = sS[0] + sS[1] + sS[2] + sS[3];
        const float tc = sC[0] + sC[1] + sC[2] + sC[3];
        out[0] = ts / (3.0f * tc);
    }
}

extern "C" void kernel_launch(void* const* d_in, const int* in_sizes, int n_in,
                              void* d_out, int out_size, void* d_ws, size_t ws_size,
                              hipStream_t stream) {
    const float* depth = (const float*)d_in[0];   // [2160][3840] f32
    const float* rgb   = (const float*)d_in[1];   // [2160][3840][3] f32
    const int*   mask  = (const int*)  d_in[2];   // [2160][3840] i32
    const float* lmat  = (const float*)d_in[3];   // [9][3] f32
    const float* K     = (const float*)d_in[4];   // [3][3] f32
    float* accum = (float*)d_ws;
    float* out   = (float*)d_out;

    const dim3 grid(NSX, NSY);                    // 16 x 135 = 2160 single-wave blocks

    if (ws_size >= (size_t)NBLOCKS * 2 * sizeof(float)) {
        shading_main<<<grid, 64, 0, stream>>>(depth, rgb, mask, lmat, K, accum, 1);
        finalize_kernel<<<1, 256, 0, stream>>>(accum, NBLOCKS, out);
    } else {
        hipMemsetAsync(accum, 0, NBINS * 2 * sizeof(float), stream);
        shading_main<<<grid, 64, 0, stream>>>(depth, rgb, mask, lmat, K, accum, 0);
        finalize_kernel<<<1, 256, 0, stream>>>(accum, NBINS, out);
    }
}

// Round 5
// 209.180 us; speedup vs baseline: 1.9543x; 1.9543x over previous
//
#include <hip/hip_runtime.h>
#include <math.h>

#define H_IMG 2160
#define W_IMG 3840
#define SPAN 252          // output cols per strip (x0+1 .. x0+252; strip 0 also owns col 0)
#define NSX 16            // 16 * 252 = 4032 >= 3840
#define HS 12             // output rows per wave
#define WPB 4             // waves per block, stacked vertically: block covers 48 rows
#define NSY 45            // 45 * 48 = 2160
#define NBLOCKS (NSX * NSY)   // 720
#define NBINS 2048

// Rolling-register fused kernel. KEY: the row loop is '#pragma unroll 1' --
// R3/R4 spilled ~300MB to scratch because full unroll let the scheduler hoist
// all rows' global loads, exploding live ranges. A rolled loop bounds load
// motion to one iteration; manual 1-row prefetch supplies the latency hiding.
__global__ __launch_bounds__(256, 3) void shading_main(
    const float* __restrict__ depth,
    const float* __restrict__ rgb,
    const int*   __restrict__ mask,
    const float* __restrict__ lmat,   // [9][3]
    const float* __restrict__ K,      // [3][3]
    float* __restrict__ accum,        // partial {S,C} pairs
    int direct)
{
    const int tid  = threadIdx.x;
    const int lane = tid & 63;
    const int wv   = tid >> 6;
    const int sx   = blockIdx.x;
    const int x0   = sx * SPAN;                    // multiple of 4
    const int y0   = blockIdx.y * (WPB * HS) + wv * HS;
    const int colBase = x0 + 4 * lane;             // 16B-aligned
    const bool fullIn = (colBase + 3) < W_IMG;     // 4-col groups: fully in or out

    // ---- Kinv (adjugate/det; uniform -> SGPRs) ----
    const float m00 = K[0], m01 = K[1], m02 = K[2];
    const float m10 = K[3], m11 = K[4], m12 = K[5];
    const float m20 = K[6], m21 = K[7], m22 = K[8];
    const float det = m00*(m11*m22 - m12*m21)
                    - m01*(m10*m22 - m12*m20)
                    + m02*(m10*m21 - m11*m20);
    const float id  = 1.0f / det;
    const float i00 = (m11*m22 - m12*m21) * id;
    const float i01 = (m02*m21 - m01*m22) * id;
    const float i02 = (m01*m12 - m02*m11) * id;
    const float i10 = (m12*m20 - m10*m22) * id;
    const float i11 = (m00*m22 - m02*m20) * id;
    const float i12 = (m02*m10 - m00*m12) * id;
    const float i20 = (m10*m21 - m11*m20) * id;
    const float i21 = (m01*m20 - m00*m21) * id;
    const float i22 = (m00*m11 - m01*m10) * id;

    float L[27];
    #pragma unroll
    for (int i = 0; i < 27; ++i) L[i] = lmat[i];   // uniform -> s_load

    // ---- output ownership: strip owns lc in [1,252] (strip 0 also lc=0) ----
    float wout[4];
    #pragma unroll
    for (int k = 0; k < 4; ++k) {
        const int c  = colBase + k;
        const int lc = 4 * lane + k;
        const bool v = (c < W_IMG) && (lc <= SPAN) && (lc >= 1 || sx == 0);
        wout[k] = v ? 1.0f : 0.0f;
    }
    const float qm1s = (lane == 0) ? 0.0f : 1.0f;  // zero-pad left edge (strip 0)

    // ---- ray at (colBase, y0-1); +Kinv col1 per row ----
    float rx = fmaf(i00, (float)colBase, fmaf(i01, (float)(y0 - 1), i02));
    float ry = fmaf(i10, (float)colBase, fmaf(i11, (float)(y0 - 1), i12));
    float rz = fmaf(i20, (float)colBase, fmaf(i21, (float)(y0 - 1), i22));

    const float4 Z4 = make_float4(0.f, 0.f, 0.f, 0.f);

    // ---- prologue: row h=y0-1 state ----
    float4 dC = Z4, dN = Z4;                 // depth rows h, h+1
    float4 raC = Z4, rbC = Z4, rcC = Z4;     // rgb row h
    int4   mC  = make_int4(0, 0, 0, 0);      // mask row h
    if (fullIn) {
        if (y0 > 0) {
            const long pix = (long)(y0 - 1) * W_IMG + colBase;
            dC  = *(const float4*)(depth + pix);
            raC = *(const float4*)(rgb + pix * 3);
            rbC = *(const float4*)(rgb + pix * 3 + 4);
            rcC = *(const float4*)(rgb + pix * 3 + 8);
            mC  = *(const int4*)(mask + pix);
        }
        dN = *(const float4*)(depth + (long)y0 * W_IMG + colBase);
    }

    // rolling state (constant indices only; becomes loop-carried phis)
    float sA0[4] = {0,0,0,0}, sA1[4] = {0,0,0,0}, sA2[4] = {0,0,0,0};
    float sB0[4] = {0,0,0,0}, sB1[4] = {0,0,0,0}, sB2[4] = {0,0,0,0};
    float qB0[4] = {0,0,0,0}, qB1[4] = {0,0,0,0}, qB2[4] = {0,0,0,0};
    float wB[4]  = {0,0,0,0};
    float accS = 0.f, accC = 0.f;

    #pragma unroll 1
    for (int j = 0; j < HS + 2; ++j) {
        const int h = y0 - 1 + j;            // row shaded this step

        // ---- prefetch next row: depth(h+2), rgb/mask(h+1) ----
        float4 dP = Z4, raN = Z4, rbN = Z4, rcN = Z4;
        int4   mN = make_int4(0, 0, 0, 0);
        if (fullIn) {
            if (h + 2 < H_IMG)
                dP = *(const float4*)(depth + (long)(h + 2) * W_IMG + colBase);
            if (h + 1 < H_IMG) {             // h+1 >= 0 always
                const long pix = (long)(h + 1) * W_IMG + colBase;
                raN = *(const float4*)(rgb + pix * 3);
                rbN = *(const float4*)(rgb + pix * 3 + 4);
                rcN = *(const float4*)(rgb + pix * 3 + 8);
                mN  = *(const int4*)(mask + pix);
            }
        }

        // ---- shade row h from regs loaded last iteration ----
        const float dcv[4] = {dC.x, dC.y, dC.z, dC.w};
        const float dnv[4] = {dN.x, dN.y, dN.z, dN.w};
        const float rrv[12] = {raC.x, raC.y, raC.z, raC.w,
                               rbC.x, rbC.y, rbC.z, rbC.w,
                               rcC.x, rcC.y, rcC.z, rcC.w};
        const int   mmv[4] = {mC.x, mC.y, mC.z, mC.w};
        const float dcR = __shfl_down(dC.x, 1, 64);    // depth(h, colBase+4)

        float qC0[4], qC1[4], qC2[4], wC[4];
        float rxk = rx, ryk = ry, rzk = rz;
        #pragma unroll
        for (int k = 0; k < 4; ++k) {
            const float d0 = dcv[k];
            const float dR = (k < 3) ? dcv[k + 1] : dcR;
            const float dD = dnv[k];
            const float px = rxk * d0, py = ryk * d0, pz = rzk * d0;
            const float ax = (rxk + i00) * dR - px;    // pl - p
            const float ay = (ryk + i10) * dR - py;
            const float az = (rzk + i20) * dR - pz;
            const float bx = (rxk + i01) * dD - px;    // pu - p
            const float by = (ryk + i11) * dD - py;
            const float bz = (rzk + i21) * dD - pz;
            float nx = ay*bz - az*by;
            float ny = az*bx - ax*bz;
            float nz = ax*by - ay*bx;
            const float nn  = nx*nx + ny*ny + nz*nz;
            const float inr = __builtin_amdgcn_rsqf(fmaxf(nn, 1e-24f)); // ==1/max(sqrt,1e-12)
            nx *= inr; ny *= inr; nz *= inr;
            const float h4 = nx*ny, h5 = ny*nz, h7 = nz*nx;
            const float nx2 = nx*nx, ny2 = ny*ny, nz2 = nz*nz;
            const float h6 = 2.f*nz2 - nx2 - ny2;
            const float h8 = nx2 - ny2;
            const float B0 = L[0] + ny*L[3] + nz*L[6] + nx*L[9]  + h4*L[12] + h5*L[15] + h6*L[18] + h7*L[21] + h8*L[24];
            const float B1 = L[1] + ny*L[4] + nz*L[7] + nx*L[10] + h4*L[13] + h5*L[16] + h6*L[19] + h7*L[22] + h8*L[25];
            const float B2 = L[2] + ny*L[5] + nz*L[8] + nx*L[11] + h4*L[14] + h5*L[17] + h6*L[20] + h7*L[23] + h8*L[26];
            const float m  = (mmv[k] > 0) ? 1.0f : 0.0f;
            qC0[k] = fmaf(m, B0, -rrv[3*k + 0]);       // q = mask*B - rgb
            qC1[k] = fmaf(m, B1, -rrv[3*k + 1]);
            qC2[k] = fmaf(m, B2, -rrv[3*k + 2]);
            wC[k]  = m * wout[k];
            rxk += i00; ryk += i10; rzk += i20;        // +Kinv col0 per col
        }

        // ---- horizontal 3-tap sums via shuffles ----
        float sC0[4], sC1[4], sC2[4];
        {
            const float a0 = __shfl_up(qC0[3], 1, 64) * qm1s;
            const float a1 = __shfl_up(qC1[3], 1, 64) * qm1s;
            const float a2 = __shfl_up(qC2[3], 1, 64) * qm1s;
            const float p0 = __shfl_down(qC0[0], 1, 64);
            const float p1 = __shfl_down(qC1[0], 1, 64);
            const float p2 = __shfl_down(qC2[0], 1, 64);

            const float t01_0 = qC0[0] + qC0[1];
            const float t12_0 = qC0[1] + qC0[2];
            const float t23_0 = qC0[2] + qC0[3];
            sC0[0] = a0 + t01_0;
            sC0[1] = t01_0 + qC0[2];
            sC0[2] = t12_0 + qC0[3];
            sC0[3] = t23_0 + p0;

            const float t01_1 = qC1[0] + qC1[1];
            const float t12_1 = qC1[1] + qC1[2];
            const float t23_1 = qC1[2] + qC1[3];
            sC1[0] = a1 + t01_1;
            sC1[1] = t01_1 + qC1[2];
            sC1[2] = t12_1 + qC1[3];
            sC1[3] = t23_1 + p1;

            const float t01_2 = qC2[0] + qC2[1];
            const float t12_2 = qC2[1] + qC2[2];
            const float t23_2 = qC2[2] + qC2[3];
            sC2[0] = a2 + t01_2;
            sC2[1] = t01_2 + qC2[2];
            sC2[2] = t12_2 + qC2[3];
            sC2[3] = t23_2 + p2;
        }

        // ---- emit row h-1: diff = q - sum3x3/9 ----
        if (j >= 2) {
            #pragma unroll
            for (int k = 0; k < 4; ++k) {
                const float v0 = sA0[k] + sB0[k] + sC0[k];
                const float v1 = sA1[k] + sB1[k] + sC1[k];
                const float v2 = sA2[k] + sB2[k] + sC2[k];
                const float d0 = fmaf(v0, -(1.f/9.f), qB0[k]);
                const float d1 = fmaf(v1, -(1.f/9.f), qB1[k]);
                const float d2 = fmaf(v2, -(1.f/9.f), qB2[k]);
                const float w  = wB[k];
                accS = fmaf(w, d0*d0 + d1*d1 + d2*d2, accS);
                accC += w;
            }
        }

        // ---- rotate (direct assignments -> phis) ----
        #pragma unroll
        for (int k = 0; k < 4; ++k) {
            sA0[k] = sB0[k]; sA1[k] = sB1[k]; sA2[k] = sB2[k];
            sB0[k] = sC0[k]; sB1[k] = sC1[k]; sB2[k] = sC2[k];
            qB0[k] = qC0[k]; qB1[k] = qC1[k]; qB2[k] = qC2[k];
            wB[k]  = wC[k];
        }
        dC = dN; dN = dP;
        raC = raN; rbC = rbN; rcC = rcN; mC = mN;
        rx += i01; ry += i11; rz += i21;               // +Kinv col1 per row
    }

    // ---- reduction: wave shuffle -> 4-slot LDS -> store/atomic ----
    #pragma unroll
    for (int off = 32; off > 0; off >>= 1) {
        accS += __shfl_down(accS, off, 64);
        accC += __shfl_down(accC, off, 64);
    }
    __shared__ float sS[WPB], sC[WPB];
    if (lane == 0) { sS[wv] = accS; sC[wv] = accC; }
    __syncthreads();
    if (tid == 0) {
        const float ts = sS[0] + sS[1] + sS[2] + sS[3];
        const float tc = sC[0] + sC[1] + sC[2] + sC[3];
        const int bid = blockIdx.y * gridDim.x + blockIdx.x;
        if (direct) {
            accum[2*bid + 0] = ts;
            accum[2*bid + 1] = tc;
        } else {
            const int bin = bid & (NBINS - 1);
            atomicAdd(&accum[2*bin + 0], ts);
            atomicAdd(&accum[2*bin + 1], tc);
        }
    }
}

__global__ __launch_bounds__(256) void finalize_kernel(
    const float* __restrict__ part, int n, float* __restrict__ out)
{
    const int tid = threadIdx.x;
    float s = 0.f, c = 0.f;
    for (int i = tid; i < n; i += 256) {
        s += part[2*i + 0];
        c += part[2*i + 1];
    }
    #pragma unroll
    for (int off = 32; off > 0; off >>= 1) {
        s += __shfl_down(s, off, 64);
        c += __shfl_down(c, off, 64);
    }
    __shared__ float sS[4], sC[4];
    const int wid = tid >> 6, lane = tid & 63;
    if (lane == 0) { sS[wid] = s; sC[wid] = c; }
    __syncthreads();
    if (tid == 0) {
        const float ts = sS[0] + sS[1] + sS[2] + sS[3];
        const float tc = sC[0] + sC[1] + sC[2] + sC[3];
        out[0] = ts / (3.0f * tc);
    }
}

extern "C" void kernel_launch(void* const* d_in, const int* in_sizes, int n_in,
                              void* d_out, int out_size, void* d_ws, size_t ws_size,
                              hipStream_t stream) {
    const float* depth = (const float*)d_in[0];   // [2160][3840] f32
    const float* rgb   = (const float*)d_in[1];   // [2160][3840][3] f32
    const int*   mask  = (const int*)  d_in[2];   // [2160][3840] i32
    const float* lmat  = (const float*)d_in[3];   // [9][3] f32
    const float* K     = (const float*)d_in[4];   // [3][3] f32
    float* accum = (float*)d_ws;
    float* out   = (float*)d_out;

    const dim3 grid(NSX, NSY);                    // 16 x 45 = 720 blocks x 4 waves

    if (ws_size >= (size_t)NBLOCKS * 2 * sizeof(float)) {
        shading_main<<<grid, 256, 0, stream>>>(depth, rgb, mask, lmat, K, accum, 1);
        finalize_kernel<<<1, 256, 0, stream>>>(accum, NBLOCKS, out);
    } else {
        hipMemsetAsync(accum, 0, NBINS * 2 * sizeof(float), stream);
        shading_main<<<grid, 256, 0, stream>>>(depth, rgb, mask, lmat, K, accum, 0);
        finalize_kernel<<<1, 256, 0, stream>>>(accum, NBINS, out);
    }
}